// Round 1
// baseline (772.610 us; speedup 1.0000x reference)
//
#include <hip/hip_runtime.h>
#include <hip/hip_bf16.h>

#define N_ATOMS 20000
#define N_EDGES 80000
#define ATOM_DIM 29
#define BOND_DIM 11
#define UNITS 64
#define STEPS 4
#define KCOLS (3*UNITS)              // 192
#define PCOLS ((BOND_DIM+1)*UNITS)   // 768 (11 bond slices + 1 bias slice)

__global__ void init_h(const float* __restrict__ atom, float* __restrict__ h) {
    int idx = blockIdx.x*256 + threadIdx.x;
    if (idx >= N_ATOMS*UNITS) return;
    int a = idx / UNITS, i = idx % UNITS;
    h[idx] = (i < ATOM_DIM) ? atom[a*ATOM_DIM + i] : 0.f;
}

// EKT[j, b*64+i] = ek[b, i*64+j]  (b<11);  EKT[j, 704+i] = eb[i*64+j]
__global__ void build_ekt(const float* __restrict__ ek, const float* __restrict__ eb,
                          float* __restrict__ ekt) {
    int idx = blockIdx.x*256 + threadIdx.x;
    if (idx >= UNITS*PCOLS) return;
    int j = idx / PCOLS, c = idx % PCOLS;
    int b = c / UNITS, i = c % UNITS;
    ekt[idx] = (b < BOND_DIM) ? ek[b*(UNITS*UNITS) + i*UNITS + j] : eb[i*UNITS + j];
}

// P[a, c] = sum_j h[a,j] * EKT[j, c]   (M=20000, K=64, N=768)
// block: 256 threads, 16 atoms; thread owns cols {tid, tid+256, tid+512}
__global__ __launch_bounds__(256) void p_kernel(const float* __restrict__ h,
    const float* __restrict__ ekt, float* __restrict__ P) {
  __shared__ float hs[16][UNITS];
  int a0 = blockIdx.x * 16;
  int tid = threadIdx.x;
  for (int idx = tid; idx < 16*UNITS; idx += 256) {
    int a = idx >> 6, j = idx & 63;
    hs[a][j] = h[(a0+a)*UNITS + j];
  }
  __syncthreads();
  float acc[16][3];
  #pragma unroll
  for (int a=0;a<16;a++) { acc[a][0]=0.f; acc[a][1]=0.f; acc[a][2]=0.f; }
  for (int j=0;j<UNITS;j++) {
    float w0 = ekt[j*PCOLS + tid];
    float w1 = ekt[j*PCOLS + tid + 256];
    float w2 = ekt[j*PCOLS + tid + 512];
    #pragma unroll
    for (int a=0;a<16;a++) {
      float hv = hs[a][j];
      acc[a][0] += hv*w0; acc[a][1] += hv*w1; acc[a][2] += hv*w2;
    }
  }
  for (int a=0;a<16;a++) {
    P[(size_t)(a0+a)*PCOLS + tid      ] = acc[a][0];
    P[(size_t)(a0+a)*PCOLS + tid + 256] = acc[a][1];
    P[(size_t)(a0+a)*PCOLS + tid + 512] = acc[a][2];
  }
}

// per edge e (one wave): t[i] = P[dst,704+i] + sum_b bond[e,b]*P[dst,b*64+i]
// then atomicAdd into msg[src, i]
__global__ __launch_bounds__(256) void edge_kernel(const int* __restrict__ pair,
    const float* __restrict__ bond, const float* __restrict__ P,
    float* __restrict__ msg) {
  int wid  = threadIdx.x >> 6;
  int lane = threadIdx.x & 63;
  int e = blockIdx.x*4 + wid;
  if (e >= N_EDGES) return;
  int src = pair[e*2+0];
  int dst = pair[e*2+1];
  const float* prow = P + (size_t)dst*PCOLS;
  float t = prow[BOND_DIM*UNITS + lane];
  #pragma unroll
  for (int b=0;b<BOND_DIM;b++) {
    t += bond[e*BOND_DIM + b] * prow[b*UNITS + lane];
  }
  atomicAdd(&msg[src*UNITS + lane], t);
}

// XM = msg@K + b0 ; HM = h@RK + b1   (weight columns in registers, tiles in LDS)
// block: 192 threads (=192 output cols), 32 atoms
__global__ __launch_bounds__(192) void gru_gemm(const float* __restrict__ msg,
    const float* __restrict__ h, const float* __restrict__ gk,
    const float* __restrict__ grk, const float* __restrict__ gbias,
    float* __restrict__ XM, float* __restrict__ HM) {
  __shared__ float ms[32][UNITS];
  __shared__ float hsh[32][UNITS];
  int a0 = blockIdx.x*32;
  int tid = threadIdx.x;
  for (int idx = tid; idx < 32*UNITS; idx += 192) {
    int a = idx >> 6, j = idx & 63;
    ms[a][j]  = msg[(size_t)(a0+a)*UNITS + j];
    hsh[a][j] = h[(size_t)(a0+a)*UNITS + j];
  }
  __syncthreads();
  float kr[UNITS], rkr[UNITS];
  #pragma unroll
  for (int j=0;j<UNITS;j++) { kr[j] = gk[j*KCOLS + tid]; rkr[j] = grk[j*KCOLS + tid]; }
  float b0 = gbias[tid], b1 = gbias[KCOLS + tid];
  for (int a=0;a<32;a++) {
    float xa = b0, ha = b1;
    #pragma unroll
    for (int j=0;j<UNITS;j++) { xa += ms[a][j]*kr[j]; ha += hsh[a][j]*rkr[j]; }
    XM[(size_t)(a0+a)*KCOLS + tid] = xa;
    HM[(size_t)(a0+a)*KCOLS + tid] = ha;
  }
}

__global__ void gate_kernel(const float* __restrict__ XM, const float* __restrict__ HM,
                            float* __restrict__ h) {
  int idx = blockIdx.x*256 + threadIdx.x;
  if (idx >= N_ATOMS*UNITS) return;
  int a = idx >> 6, i = idx & 63;
  const float* xm = XM + (size_t)a*KCOLS;
  const float* hm = HM + (size_t)a*KCOLS;
  float xz = xm[i], xr = xm[UNITS+i], xh = xm[2*UNITS+i];
  float rz = hm[i], rr = hm[UNITS+i], rh = hm[2*UNITS+i];
  float z = 1.f/(1.f + __expf(-(xz+rz)));
  float r = 1.f/(1.f + __expf(-(xr+rr)));
  float hh = tanhf(xh + r*rh);
  float hold = h[idx];
  h[idx] = z*hold + (1.f - z)*hh;
}

extern "C" void kernel_launch(void* const* d_in, const int* in_sizes, int n_in,
                              void* d_out, int out_size, void* d_ws, size_t ws_size,
                              hipStream_t stream) {
  const float* atom  = (const float*)d_in[0];
  const float* bond  = (const float*)d_in[1];
  const int*   pair  = (const int*)d_in[2];
  const float* ek    = (const float*)d_in[3];
  const float* eb    = (const float*)d_in[4];
  const float* gk    = (const float*)d_in[5];
  const float* grk   = (const float*)d_in[6];
  const float* gbias = (const float*)d_in[7];

  float* h   = (float*)d_out;                       // h lives in d_out (20000x64 fp32)
  float* ws  = (float*)d_ws;
  float* ekt = ws;                                  // 64*768       = 49152
  float* P   = ekt + (size_t)UNITS*PCOLS;           // 20000*768    = 15.36M
  float* msg = P   + (size_t)N_ATOMS*PCOLS;         // 20000*64     = 1.28M
  float* XM  = msg + (size_t)N_ATOMS*UNITS;         // 20000*192
  float* HM  = XM  + (size_t)N_ATOMS*KCOLS;         // 20000*192

  init_h<<<(N_ATOMS*UNITS+255)/256, 256, 0, stream>>>(atom, h);
  build_ekt<<<(UNITS*PCOLS+255)/256, 256, 0, stream>>>(ek, eb, ekt);

  for (int s=0; s<STEPS; s++) {
    p_kernel<<<N_ATOMS/16, 256, 0, stream>>>(h, ekt, P);
    hipMemsetAsync(msg, 0, (size_t)N_ATOMS*UNITS*sizeof(float), stream);
    edge_kernel<<<N_EDGES/4, 256, 0, stream>>>(pair, bond, P, msg);
    gru_gemm<<<N_ATOMS/32, 192, 0, stream>>>(msg, h, gk, grk, gbias, XM, HM);
    gate_kernel<<<(N_ATOMS*UNITS+255)/256, 256, 0, stream>>>(XM, HM, h);
  }
}

// Round 2
// 505.488 us; speedup vs baseline: 1.5284x; 1.5284x over previous
//
#include <hip/hip_runtime.h>

#define N_ATOMS 20000
#define N_EDGES 80000
#define ATOM_DIM 29
#define BOND_DIM 11
#define UNITS 64
#define STEPS 4
#define PCOLS ((BOND_DIM+1)*UNITS)   // 768 (11 bond slices + 1 bias slice)

__global__ void init_h(const float* __restrict__ atom, float* __restrict__ h) {
    int idx = blockIdx.x*256 + threadIdx.x;
    if (idx >= N_ATOMS*UNITS) return;
    int a = idx / UNITS, i = idx % UNITS;
    h[idx] = (i < ATOM_DIM) ? atom[a*ATOM_DIM + i] : 0.f;
}

// EKT[j, b*64+i] = ek[b, i*64+j]  (b<11);  EKT[j, 704+i] = eb[i*64+j]
__global__ void build_ekt(const float* __restrict__ ek, const float* __restrict__ eb,
                          float* __restrict__ ekt) {
    int idx = blockIdx.x*256 + threadIdx.x;
    if (idx >= UNITS*PCOLS) return;
    int j = idx / PCOLS, c = idx % PCOLS;
    int b = c / UNITS, i = c % UNITS;
    ekt[idx] = (b < BOND_DIM) ? ek[b*(UNITS*UNITS) + i*UNITS + j] : eb[i*UNITS + j];
}

// W2[j][c], j in [0,128), c = comp*64+i, comp: 0=zsum 1=rsum 2=xh 3=rh
// j<64: msg-part (gk); j>=64: h-part (grk)
__global__ void build_w2(const float* __restrict__ gk, const float* __restrict__ grk,
                         const float* __restrict__ gb, float* __restrict__ W2,
                         float* __restrict__ bias2) {
    int idx = blockIdx.x*256 + threadIdx.x;
    if (idx < 256) {
        int comp = idx >> 6, i = idx & 63;
        float b;
        if (comp == 0)      b = gb[i]       + gb[192 + i];
        else if (comp == 1) b = gb[64 + i]  + gb[192 + 64 + i];
        else if (comp == 2) b = gb[128 + i];
        else                b = gb[192 + 128 + i];
        bias2[idx] = b;
    }
    if (idx >= 128*256) return;
    int j = idx >> 8, c = idx & 255;
    int comp = c >> 6, i = c & 63;
    float v;
    if (j < 64) {
        v = (comp == 0) ? gk[j*192 + i]
          : (comp == 1) ? gk[j*192 + 64 + i]
          : (comp == 2) ? gk[j*192 + 128 + i] : 0.f;
    } else {
        int jj = j - 64;
        v = (comp == 0) ? grk[jj*192 + i]
          : (comp == 1) ? grk[jj*192 + 64 + i]
          : (comp == 3) ? grk[jj*192 + 128 + i] : 0.f;
    }
    W2[idx] = v;
}

// P = h @ EKT : M=20000, K=64, N=768. grid (ceil(20000/64), 3). Block 256.
// Thread (tx=tid&31, ty=tid>>5): rows ty*8+0..7, cols cb + q*64 + tx*2 + {0,1}
__global__ __launch_bounds__(256) void p_gemm(const float* __restrict__ h,
    const float* __restrict__ ekt, float* __restrict__ P) {
  __shared__ float Xs[64][36];
  __shared__ float Ws[32][256];
  int a0 = blockIdx.x * 64;
  int cb = blockIdx.y * 256;
  int tid = threadIdx.x;
  int tx = tid & 31, ty = tid >> 5;
  float acc[8][4][2];
  #pragma unroll
  for (int i=0;i<8;i++) for (int q=0;q<4;q++) { acc[i][q][0]=0.f; acc[i][q][1]=0.f; }

  for (int kt = 0; kt < 2; kt++) {
    // stage Xs: 64 rows x 32 k
    {
      int r = tid >> 2, kk = (tid & 3) * 8;
      int ar = a0 + r; if (ar >= N_ATOMS) ar = N_ATOMS - 1;
      const float* src = &h[(size_t)ar*UNITS + kt*32 + kk];
      *(float4*)&Xs[r][kk]     = *(const float4*)&src[0];
      *(float4*)&Xs[r][kk + 4] = *(const float4*)&src[4];
    }
    // stage Ws: 32 rows x 256 cols of ekt
    {
      int jr = tid >> 3, c0 = (tid & 7) * 32;
      const float* src = &ekt[(size_t)(kt*32 + jr)*PCOLS + cb + c0];
      #pragma unroll
      for (int v = 0; v < 8; v++)
        *(float4*)&Ws[jr][c0 + v*4] = *(const float4*)&src[v*4];
    }
    __syncthreads();
    #pragma unroll
    for (int k = 0; k < 32; k++) {
      float xv[8];
      #pragma unroll
      for (int i=0;i<8;i++) xv[i] = Xs[ty*8 + i][k];
      #pragma unroll
      for (int q=0;q<4;q++) {
        float2 w = *(const float2*)&Ws[k][q*64 + tx*2];
        #pragma unroll
        for (int i=0;i<8;i++) { acc[i][q][0] += xv[i]*w.x; acc[i][q][1] += xv[i]*w.y; }
      }
    }
    __syncthreads();
  }
  #pragma unroll
  for (int i=0;i<8;i++) {
    int a = a0 + ty*8 + i;
    if (a >= N_ATOMS) break;
    #pragma unroll
    for (int q=0;q<4;q++) {
      *(float2*)&P[(size_t)a*PCOLS + cb + q*64 + tx*2] = make_float2(acc[i][q][0], acc[i][q][1]);
    }
  }
}

// per edge e (one wave): t[i] = P[dst,704+i] + sum_b bond[e,b]*P[dst,b*64+i]
__global__ __launch_bounds__(256) void edge_kernel(const int* __restrict__ pair,
    const float* __restrict__ bond, const float* __restrict__ P,
    float* __restrict__ msg) {
  int wid  = threadIdx.x >> 6;
  int lane = threadIdx.x & 63;
  int e = blockIdx.x*4 + wid;
  if (e >= N_EDGES) return;
  int src = pair[e*2+0];
  int dst = pair[e*2+1];
  const float* prow = P + (size_t)dst*PCOLS;
  float t = prow[BOND_DIM*UNITS + lane];
  #pragma unroll
  for (int b=0;b<BOND_DIM;b++) {
    t += bond[e*BOND_DIM + b] * prow[b*UNITS + lane];
  }
  atomicAdd(&msg[src*UNITS + lane], t);
}

// Fused GRU: [msg|h](20000x128) @ W2(128x256) + bias2 -> gates -> h update.
// grid 625, block 256. BM=32 rows. Thread: rows ty*4+0..3, units tx*2+{0,1},
// comps q=0..3 at cols q*64 + tx*2.
__global__ __launch_bounds__(256) void gru_fused(const float* __restrict__ msg,
    float* __restrict__ h, const float* __restrict__ W2,
    const float* __restrict__ bias2) {
  __shared__ float Xs[32][36];
  __shared__ float Ws[32][256];
  int a0 = blockIdx.x * 32;
  int tid = threadIdx.x;
  int tx = tid & 31, ty = tid >> 5;
  float acc[4][4][2];
  #pragma unroll
  for (int i=0;i<4;i++) for (int q=0;q<4;q++) { acc[i][q][0]=0.f; acc[i][q][1]=0.f; }

  for (int kt = 0; kt < 4; kt++) {
    // stage Xs: 32 rows x 32 k ; k-global = kt*32+kk : <64 -> msg, else h
    {
      int r = tid >> 3, kk = (tid & 7) * 4;
      const float* xsrc = (kt < 2) ? msg : h;
      int koff = (kt < 2) ? kt*32 : (kt-2)*32;
      *(float4*)&Xs[r][kk] = *(const float4*)&xsrc[(size_t)(a0 + r)*UNITS + koff + kk];
    }
    // stage Ws: rows kt*32..+32 of W2
    {
      int jr = tid >> 3, c0 = (tid & 7) * 32;
      const float* src = &W2[(size_t)(kt*32 + jr)*256 + c0];
      #pragma unroll
      for (int v = 0; v < 8; v++)
        *(float4*)&Ws[jr][c0 + v*4] = *(const float4*)&src[v*4];
    }
    __syncthreads();
    #pragma unroll
    for (int k = 0; k < 32; k++) {
      float xv[4];
      #pragma unroll
      for (int i=0;i<4;i++) xv[i] = Xs[ty*4 + i][k];
      #pragma unroll
      for (int q=0;q<4;q++) {
        float2 w = *(const float2*)&Ws[k][q*64 + tx*2];
        #pragma unroll
        for (int i=0;i<4;i++) { acc[i][q][0] += xv[i]*w.x; acc[i][q][1] += xv[i]*w.y; }
      }
    }
    __syncthreads();
  }

  float2 bz  = *(const float2*)&bias2[tx*2];
  float2 br  = *(const float2*)&bias2[64  + tx*2];
  float2 bh  = *(const float2*)&bias2[128 + tx*2];
  float2 brh = *(const float2*)&bias2[192 + tx*2];
  #pragma unroll
  for (int i=0;i<4;i++) {
    int a = a0 + ty*4 + i;
    float2 hold = *(const float2*)&h[(size_t)a*UNITS + tx*2];
    float hn[2];
    #pragma unroll
    for (int u=0; u<2; u++) {
      float holdv = u ? hold.y : hold.x;
      float zs = acc[i][0][u] + (u ? bz.y  : bz.x);
      float rs = acc[i][1][u] + (u ? br.y  : br.x);
      float xh = acc[i][2][u] + (u ? bh.y  : bh.x);
      float rh = acc[i][3][u] + (u ? brh.y : brh.x);
      float z = 1.f/(1.f + __expf(-zs));
      float r = 1.f/(1.f + __expf(-rs));
      float hh = tanhf(xh + r*rh);
      hn[u] = z*holdv + (1.f - z)*hh;
    }
    *(float2*)&h[(size_t)a*UNITS + tx*2] = make_float2(hn[0], hn[1]);
  }
}

extern "C" void kernel_launch(void* const* d_in, const int* in_sizes, int n_in,
                              void* d_out, int out_size, void* d_ws, size_t ws_size,
                              hipStream_t stream) {
  const float* atom  = (const float*)d_in[0];
  const float* bond  = (const float*)d_in[1];
  const int*   pair  = (const int*)d_in[2];
  const float* ek    = (const float*)d_in[3];
  const float* eb    = (const float*)d_in[4];
  const float* gk    = (const float*)d_in[5];
  const float* grk   = (const float*)d_in[6];
  const float* gbias = (const float*)d_in[7];

  float* h     = (float*)d_out;                      // 20000x64 fp32
  float* ws    = (float*)d_ws;
  float* ekt   = ws;                                 // 64*768
  float* W2    = ekt + (size_t)UNITS*PCOLS;          // 128*256
  float* bias2 = W2 + 128*256;                       // 256
  float* P     = bias2 + 256;                        // 20000*768
  float* msg   = P + (size_t)N_ATOMS*PCOLS;          // 20000*64

  init_h<<<(N_ATOMS*UNITS+255)/256, 256, 0, stream>>>(atom, h);
  build_ekt<<<(UNITS*PCOLS+255)/256, 256, 0, stream>>>(ek, eb, ekt);
  build_w2<<<(128*256+255)/256, 256, 0, stream>>>(gk, grk, gbias, W2, bias2);

  for (int s=0; s<STEPS; s++) {
    p_gemm<<<dim3((N_ATOMS+63)/64, 3), 256, 0, stream>>>(h, ekt, P);
    hipMemsetAsync(msg, 0, (size_t)N_ATOMS*UNITS*sizeof(float), stream);
    edge_kernel<<<N_EDGES/4, 256, 0, stream>>>(pair, bond, P, msg);
    gru_fused<<<N_ATOMS/32, 256, 0, stream>>>(msg, h, W2, bias2);
  }
}